// Round 1
// baseline (235.086 us; speedup 1.0000x reference)
//
#include <hip/hip_runtime.h>
#include <hip/hip_cooperative_groups.h>
#include <math.h>

namespace cg = cooperative_groups;

// ---------------- problem constants ----------------
#define BB   16      // batch
#define TT   50      // targets per image
#define BT   (BB*TT) // 800
#define NCLS 80
#define IMGF 608.0f

#define H0 76
#define H1 38
#define H2 19
#define N0 277248   // 16*3*76*76
#define N1 69312    // 16*3*38*38
#define N2 17328    // 16*3*19*19
#define NTOT (N0+N1+N2)   // 363888

// noobj: 8 cells per thread -> 8 loads in flight (R5 post-mortem: one load per
// thread was latency-bound; Little's law needs MLP, not BW)
#define CELLS_PER_THREAD 8
#define NOOBJ_BLOCKS ((NTOT + 256*CELLS_PER_THREAD - 1) / (256*CELLS_PER_THREAD))  // 178

#define POS_BLOCKS_PER_SCALE 200               // 4 waves/block * 200 = 800 orders
#define NPOS_BLOCKS (3*POS_BLOCKS_PER_SCALE)   // 600
#define NBLK (NOOBJ_BLOCKS + NPOS_BLOCKS)      // 778

__constant__ float c_anchors[3][3][2] = {
    {{12.f,16.f},{19.f,36.f},{40.f,28.f}},
    {{36.f,75.f},{76.f,55.f},{72.f,146.f}},
    {{142.f,110.f},{192.f,243.f},{459.f,401.f}}};
__constant__ int c_H[3] = {H0, H1, H2};

__device__ __forceinline__ float sigmoidf_(float x) { return 1.0f / (1.0f + expf(-x)); }
__device__ __forceinline__ float clipf_(float x, float lo, float hi) {
    return fminf(fmaxf(x, lo), hi);
}

__device__ __forceinline__ float iou4(float ax, float ay, float aw, float ah,
                                      float bx, float by, float bw, float bh) {
    float ax1 = ax - aw * 0.5f, ay1 = ay - ah * 0.5f;
    float ax2 = ax + aw * 0.5f, ay2 = ay + ah * 0.5f;
    float bx1 = bx - bw * 0.5f, by1 = by - bh * 0.5f;
    float bx2 = bx + bw * 0.5f, by2 = by + bh * 0.5f;
    float iw = fmaxf(fminf(ax2, bx2) - fmaxf(ax1, bx1), 0.f);
    float ih = fmaxf(fminf(ay2, by2) - fmaxf(ay1, by1), 0.f);
    float inter = iw * ih;
    float uni = (ax2 - ax1) * (ay2 - ay1) + (bx2 - bx1) * (by2 - by1) - inter + 1e-7f;
    return inter / uni;
}

// anchor match + cell for one (scale, target row). returns -1 if invalid target
__device__ __forceinline__ int target_cell(const float* tr, int s, float& cx, float& cy,
                                           float& w, float& h, int& best, int& gxi, int& gyi) {
    float t4 = tr[4];
    if (!(t4 > 0.f)) return -1;
    cx = clipf_(tr[0], 0.f, 1.f);
    cy = clipf_(tr[1], 0.f, 1.f);
    w  = clipf_(tr[2], 0.f, 1.f);
    h  = clipf_(tr[3], 0.f, 1.f);
    best = 0;
    float bi = -1e30f;
    #pragma unroll
    for (int a = 0; a < 3; a++) {
        float aw = c_anchors[s][a][0] / IMGF;
        float ah = c_anchors[s][a][1] / IMGF;
        float v = iou4(0.5f, 0.5f, aw, ah, cx, cy, w, h);
        if (v > bi) { bi = v; best = a; }  // first-max == jnp.argmax
    }
    int H = c_H[s];
    gxi = (int)(cx * (float)H); gxi = min(max(gxi, 0), H - 1);
    gyi = (int)(cy * (float)H); gyi = min(max(gyi, 0), H - 1);
    return 0;
}

// ---- single cooperative kernel (R6): blocks [0,NOOBJ_BLOCKS) = noobj BCE
//      (8 cells/thread); blocks [NOOBJ_BLOCKS,NBLK) = positive waves;
//      grid.sync(); block 0 does the final combine (L2-hot partials).
//      This replaces the k_final dispatch + its graph dependency bubble.
//      (R5's per-block fence+atomic protocol stays dead — HW grid barrier
//      handles cross-XCD visibility.) ----
__global__ __launch_bounds__(256, 4) void k_all(const float* __restrict__ p0,
                                                const float* __restrict__ p1,
                                                const float* __restrict__ p2,
                                                const float* __restrict__ targets,
                                                float* __restrict__ noobj_part,   // [NOOBJ_BLOCKS*3]
                                                float* __restrict__ pos_part,     // [NPOS_BLOCKS*5]
                                                float* __restrict__ out) {
    int blk = blockIdx.x;
    int lane = threadIdx.x & 63;
    int wv = threadIdx.x >> 6;

    __shared__ float sm3[4][3];
    __shared__ float sm5[4][5];
    __shared__ float fin[4][18];

    if (blk < NOOBJ_BLOCKS) {
        // ---------- no-object BCE, 8 independent strided loads per thread ----------
        int base = blk * (256 * CELLS_PER_THREAD) + threadIdx.x;
        float vals[CELLS_PER_THREAD];
        #pragma unroll
        for (int k = 0; k < CELLS_PER_THREAD; k++) {
            int g = base + k * 256;
            const float* pred; int c;
            if (g < N0)            { pred = p0; c = g; }
            else if (g < N0 + N1)  { pred = p1; c = g - N0; }
            else                   { pred = p2; c = g - N0 - N1; }
            vals[k] = (g < NTOT) ? pred[(long long)c * 85 + 4] : 0.f;  // all 8 loads issue before use
        }
        float sum[3] = {0.f, 0.f, 0.f};
        #pragma unroll
        for (int k = 0; k < CELLS_PER_THREAD; k++) {
            int g = base + k * 256;
            if (g < NTOT) {
                // -log1p(-clip(sigmoid(x),1e-10,1-1e-10)) == min(softplus(x), -ln(1e-10))
                // (kills the non-fast-math f32 divide; lower clip differs by <=1e-10, dead
                //  for N(0,1) inputs)
                float x = vals[k];
                float sp = fmaxf(x, 0.f) + log1pf(expf(-fabsf(x)));
                float v = fminf(sp, 23.02585093f);
                if (g < N0)           sum[0] += v;
                else if (g < N0 + N1) sum[1] += v;
                else                  sum[2] += v;
            }
        }
        #pragma unroll
        for (int off = 32; off > 0; off >>= 1) {
            sum[0] += __shfl_xor(sum[0], off, 64);
            sum[1] += __shfl_xor(sum[1], off, 64);
            sum[2] += __shfl_xor(sum[2], off, 64);
        }
        if (lane == 0) { sm3[wv][0] = sum[0]; sm3[wv][1] = sum[1]; sm3[wv][2] = sum[2]; }
        __syncthreads();
        if (threadIdx.x < 3)
            noobj_part[blk * 3 + threadIdx.x] =
                sm3[0][threadIdx.x] + sm3[1][threadIdx.x] + sm3[2][threadIdx.x] + sm3[3][threadIdx.x];
    } else {
        // ---------- positive cells: one WAVE per (scale, order) ----------
        int bp = blk - NOOBJ_BLOCKS;
        int s = bp / POS_BLOCKS_PER_SCALE;
        int order = (bp % POS_BLOCKS_PER_SCALE) * 4 + wv;   // < 800

        float v_coord = 0.f, v_obj = 0.f, v_noadj = 0.f, v_cls = 0.f, v_np = 0.f;

        int b = order / TT, t = order % TT;
        const float* tr = targets + order * 85;
        float cx, cy, w, h; int best, gxi, gyi;
        if (target_cell(tr, s, cx, cy, w, h, best, gxi, gyi) == 0) {  // wave-uniform
            int H = c_H[s];
            int flat = ((b * 3 + best) * H + gyi) * H + gxi;

            // inline last-write-wins: any LATER valid target in this image on same cell?
            bool lost = false;
            int tp = t + 1 + lane;
            if (tp < TT) {
                const float* tr2 = targets + (b * TT + tp) * 85;
                float cx2, cy2, w2, h2; int best2, gxi2, gyi2;
                if (target_cell(tr2, s, cx2, cy2, w2, h2, best2, gxi2, gyi2) == 0) {
                    int flat2 = ((b * 3 + best2) * H + gyi2) * H + gxi2;
                    lost = (flat2 == flat);
                }
            }
            if (__ballot(lost) == 0ull) {   // this order wins the cell
                const float* pred = (s == 0) ? p0 : (s == 1) ? p1 : p2;
                const float* pc = pred + (long long)flat * 85;

                float px = sigmoidf_(pc[0]);
                float py = sigmoidf_(pc[1]);
                float bx = clipf_((px + (float)gxi) / (float)H, 0.f, 1.f);
                float by = clipf_((py + (float)gyi) / (float)H, 0.f, 1.f);
                float aw = c_anchors[s][best][0], ah = c_anchors[s][best][1];
                float bwv = clipf_(expf(clipf_(pc[2], -10.f, 10.f)) * aw / IMGF, 0.f, 1.f);
                float bhv = clipf_(expf(clipf_(pc[3], -10.f, 10.f)) * ah / IMGF, 0.f, 1.f);
                float iou = iou4(bx, by, bwv, bhv, cx, cy, w, h);

                float p = clipf_(sigmoidf_(pc[4]), 1e-10f, 1.0f);

                // class BCE split across lanes: lane k -> class k (+ class k+64 if k<16)
                float pcv = clipf_(sigmoidf_(pc[5 + lane]), 1e-10f, 1.0f);
                float tc  = clipf_(tr[5 + lane], 0.f, 1.f);
                float cl  = -(tc * logf(pcv) + (1.f - tc) * log1pf(-pcv));
                if (lane < NCLS - 64) {
                    float pcv2 = clipf_(sigmoidf_(pc[5 + 64 + lane]), 1e-10f, 1.0f);
                    float tc2  = clipf_(tr[5 + 64 + lane], 0.f, 1.f);
                    cl += -(tc2 * logf(pcv2) + (1.f - tc2) * log1pf(-pcv2));
                }
                #pragma unroll
                for (int off = 32; off > 0; off >>= 1) cl += __shfl_xor(cl, off, 64);

                v_coord = 1.f - iou;
                v_obj   = -logf(p);
                v_noadj = -log1pf(-p);
                v_cls   = cl;
                v_np    = 1.f;
            }
        }

        if (lane == 0) {
            sm5[wv][0] = v_coord; sm5[wv][1] = v_obj; sm5[wv][2] = v_noadj;
            sm5[wv][3] = v_cls;   sm5[wv][4] = v_np;
        }
        __syncthreads();
        if (threadIdx.x < 5) {
            pos_part[bp * 5 + threadIdx.x] =
                sm5[0][threadIdx.x] + sm5[1][threadIdx.x] +
                sm5[2][threadIdx.x] + sm5[3][threadIdx.x];
        }
    }

    // -------- grid-wide barrier (device-scope release/acquire included) --------
    cg::this_grid().sync();

    // -------- final combine: block 0 only, partials are L2-hot --------
    if (blk == 0) {
        // acc[0..2] = noobj sums per scale; acc[3+s*5+q] = pos partial q of scale s.
        // All indices compile-time static (rule #20: runtime-indexed arrays -> scratch).
        float acc[18];
        #pragma unroll
        for (int r = 0; r < 18; r++) acc[r] = 0.f;

        if (threadIdx.x < NOOBJ_BLOCKS) {          // 178 < 256: single load round
            acc[0] = noobj_part[threadIdx.x * 3 + 0];
            acc[1] = noobj_part[threadIdx.x * 3 + 1];
            acc[2] = noobj_part[threadIdx.x * 3 + 2];
        }
        #pragma unroll
        for (int r = 0; r < 3; r++) {              // ceil(600/256) = 3 rounds
            int i = threadIdx.x + r * 256;
            if (i < NPOS_BLOCKS) {
                float v0 = pos_part[i * 5 + 0];
                float v1 = pos_part[i * 5 + 1];
                float v2 = pos_part[i * 5 + 2];
                float v3 = pos_part[i * 5 + 3];
                float v4 = pos_part[i * 5 + 4];
                int s = i / POS_BLOCKS_PER_SCALE;
                if (s == 0)      { acc[3]  += v0; acc[4]  += v1; acc[5]  += v2; acc[6]  += v3; acc[7]  += v4; }
                else if (s == 1) { acc[8]  += v0; acc[9]  += v1; acc[10] += v2; acc[11] += v3; acc[12] += v4; }
                else             { acc[13] += v0; acc[14] += v1; acc[15] += v2; acc[16] += v3; acc[17] += v4; }
            }
        }

        #pragma unroll
        for (int off = 32; off > 0; off >>= 1) {
            #pragma unroll
            for (int r = 0; r < 18; r++) acc[r] += __shfl_xor(acc[r], off, 64);
        }
        if (lane == 0) {
            #pragma unroll
            for (int r = 0; r < 18; r++) fin[wv][r] = acc[r];
        }
        __syncthreads();
        if (threadIdx.x == 0) {
            const float ncell[3] = {(float)N0, (float)N1, (float)N2};
            float coord = 0.f, conf = 0.f, cls = 0.f;
            #pragma unroll
            for (int s = 0; s < 3; s++) {
                float noobjTot = fin[0][s] + fin[1][s] + fin[2][s] + fin[3][s];
                float co    = fin[0][3 + s * 5 + 0] + fin[1][3 + s * 5 + 0] + fin[2][3 + s * 5 + 0] + fin[3][3 + s * 5 + 0];
                float ob    = fin[0][3 + s * 5 + 1] + fin[1][3 + s * 5 + 1] + fin[2][3 + s * 5 + 1] + fin[3][3 + s * 5 + 1];
                float noadj = fin[0][3 + s * 5 + 2] + fin[1][3 + s * 5 + 2] + fin[2][3 + s * 5 + 2] + fin[3][3 + s * 5 + 2];
                float cl    = fin[0][3 + s * 5 + 3] + fin[1][3 + s * 5 + 3] + fin[2][3 + s * 5 + 3] + fin[3][3 + s * 5 + 3];
                float npos  = fin[0][3 + s * 5 + 4] + fin[1][3 + s * 5 + 4] + fin[2][3 + s * 5 + 4] + fin[3][3 + s * 5 + 4];
                float nneg = ncell[s] - npos;
                float dn = fmaxf(npos, 1.f);
                conf += ob / dn + 0.5f * (noobjTot - noadj) / fmaxf(nneg, 1.f);
                if (npos > 0.f) {
                    coord += co / dn;
                    cls   += cl / fmaxf(npos * (float)NCLS, 1.f);
                }
            }
            out[0] = 5.0f * coord + conf + 1.0f * cls;
            out[1] = coord;
            out[2] = conf;
            out[3] = cls;
        }
    }
}

extern "C" void kernel_launch(void* const* d_in, const int* in_sizes, int n_in,
                              void* d_out, int out_size, void* d_ws, size_t ws_size,
                              hipStream_t stream) {
    const float* p0 = (const float*)d_in[0];
    const float* p1 = (const float*)d_in[1];
    const float* p2 = (const float*)d_in[2];
    const float* tg = (const float*)d_in[3];
    float* out = (float*)d_out;

    char* ws = (char*)d_ws;
    float* noobj_part = (float*)ws;              // NOOBJ_BLOCKS*3 floats (2136 B)
    float* pos_part   = (float*)(ws + 4096);     // NPOS_BLOCKS*5 floats (12000 B)

    void* kargs[] = {(void*)&p0, (void*)&p1, (void*)&p2, (void*)&tg,
                     (void*)&noobj_part, (void*)&pos_part, (void*)&out};
    hipLaunchCooperativeKernel((const void*)k_all, dim3(NBLK), dim3(256), kargs, 0, stream);
}

// Round 2
// 177.878 us; speedup vs baseline: 1.3216x; 1.3216x over previous
//
#include <hip/hip_runtime.h>
#include <math.h>

// ---------------- problem constants ----------------
#define BB   16      // batch
#define TT   50      // targets per image
#define NCLS 80
#define IMGF 608.0f

#define H0 76
#define H1 38
#define H2 19
#define N0 277248   // 16*3*76*76
#define N1 69312    // 16*3*38*38
#define N2 17328    // 16*3*19*19
#define NTOT (N0+N1+N2)   // 363888

// float4 counts per scale (N*85/4 — all divisible by 4, no float4 straddles arrays)
#define C0 5891520
#define C1 1472880
#define C2 368220
#define FTOT (C0+C1+C2)   // 7732620 float4s = 115.5 MB

// pos: one WAVE per (scale, order). 200 blocks/scale * 4 waves = 800 orders.
#define POS_BLOCKS_PER_SCALE 200
#define NPOS_BLOCKS (3*POS_BLOCKS_PER_SCALE)   // 600

// noobj (R7): full coalesced float4 STREAM of all pred data instead of the
// ch4 gather. R1 post-mortem: gather = 64 distinct 64B lines per wave instr,
// sustained only ~600 GB/s (latency-bound); streaming 5x the bytes at the
// 6.3 TB/s float4 ceiling is ~19us vs ~40us. 1024 blocks, 30 float4/thread,
// 5 loads in flight per chunk.
#define NOB 1024
#define F4_PER_THREAD 30          // 1024*256*30 = 7864320 >= FTOT
#define NBLK (NPOS_BLOCKS + NOB)  // 1624

__constant__ float c_anchors[3][3][2] = {
    {{12.f,16.f},{19.f,36.f},{40.f,28.f}},
    {{36.f,75.f},{76.f,55.f},{72.f,146.f}},
    {{142.f,110.f},{192.f,243.f},{459.f,401.f}}};
__constant__ int c_H[3] = {H0, H1, H2};

__device__ __forceinline__ float sigmoidf_(float x) { return 1.0f / (1.0f + expf(-x)); }
__device__ __forceinline__ float clipf_(float x, float lo, float hi) {
    return fminf(fmaxf(x, lo), hi);
}

__device__ __forceinline__ float iou4(float ax, float ay, float aw, float ah,
                                      float bx, float by, float bw, float bh) {
    float ax1 = ax - aw * 0.5f, ay1 = ay - ah * 0.5f;
    float ax2 = ax + aw * 0.5f, ay2 = ay + ah * 0.5f;
    float bx1 = bx - bw * 0.5f, by1 = by - bh * 0.5f;
    float bx2 = bx + bw * 0.5f, by2 = by + bh * 0.5f;
    float iw = fmaxf(fminf(ax2, bx2) - fmaxf(ax1, bx1), 0.f);
    float ih = fmaxf(fminf(ay2, by2) - fmaxf(ay1, by1), 0.f);
    float inter = iw * ih;
    float uni = (ax2 - ax1) * (ay2 - ay1) + (bx2 - bx1) * (by2 - by1) - inter + 1e-7f;
    return inter / uni;
}

// anchor match + cell for one (scale, target row). returns -1 if invalid target
__device__ __forceinline__ int target_cell(const float* tr, int s, float& cx, float& cy,
                                           float& w, float& h, int& best, int& gxi, int& gyi) {
    float t4 = tr[4];
    if (!(t4 > 0.f)) return -1;
    cx = clipf_(tr[0], 0.f, 1.f);
    cy = clipf_(tr[1], 0.f, 1.f);
    w  = clipf_(tr[2], 0.f, 1.f);
    h  = clipf_(tr[3], 0.f, 1.f);
    best = 0;
    float bi = -1e30f;
    #pragma unroll
    for (int a = 0; a < 3; a++) {
        float aw = c_anchors[s][a][0] / IMGF;
        float ah = c_anchors[s][a][1] / IMGF;
        float v = iou4(0.5f, 0.5f, aw, ah, cx, cy, w, h);
        if (v > bi) { bi = v; best = a; }  // first-max == jnp.argmax
    }
    int H = c_H[s];
    gxi = (int)(cx * (float)H); gxi = min(max(gxi, 0), H - 1);
    gyi = (int)(cy * (float)H); gyi = min(max(gyi, 0), H - 1);
    return 0;
}

// ---- main kernel: blocks [0,600) = positive waves (unchanged, verified);
//      blocks [600,1624) = noobj coalesced stream. Two-dispatch structure
//      kept: R6 post-mortem confirmed grid-wide sync costs ~50us on 8 XCDs
//      (matches R5's completion-protocol finding) vs ~5-10us dispatch bubble. ----
__global__ __launch_bounds__(256) void k_main(const float* __restrict__ p0,
                                              const float* __restrict__ p1,
                                              const float* __restrict__ p2,
                                              const float* __restrict__ targets,
                                              float* __restrict__ noobj_part,   // [NOB*3]
                                              float* __restrict__ pos_part) {   // [NPOS_BLOCKS*5]
    int blk = blockIdx.x;
    int lane = threadIdx.x & 63;
    int wv = threadIdx.x >> 6;

    __shared__ float sm3[4][3];
    __shared__ float sm5[4][5];

    if (blk >= NPOS_BLOCKS) {
        // ---------- no-object BCE: coalesced float4 stream over p0|p1|p2 ----------
        int nb = blk - NPOS_BLOCKS;                 // [0,1024)
        int gbase = nb * (F4_PER_THREAD * 256) + threadIdx.x;
        const float4* pv0 = (const float4*)p0;
        const float4* pv1 = (const float4*)p1;
        const float4* pv2 = (const float4*)p2;

        float s0 = 0.f, s1 = 0.f, s2 = 0.f;
        #pragma unroll 1
        for (int c = 0; c < 6; c++) {               // 6 chunks x 5 float4s = 30
            float4 v[5];
            #pragma unroll
            for (int j = 0; j < 5; j++) {           // 5 loads in flight (MLP)
                int g = gbase + (c * 5 + j) * 256;
                const float4* pp; int q;
                if (g < C0)            { pp = pv0; q = g; }
                else if (g < C0 + C1)  { pp = pv1; q = g - C0; }
                else                   { pp = pv2; q = g - (C0 + C1); }
                v[j] = (g < FTOT) ? pp[q] : make_float4(0.f, 0.f, 0.f, 0.f);
            }
            #pragma unroll
            for (int j = 0; j < 5; j++) {
                int g = gbase + (c * 5 + j) * 256;
                if (g < FTOT) {
                    unsigned q = (g < C0) ? (unsigned)g
                               : (g < C0 + C1) ? (unsigned)(g - C0)
                               : (unsigned)(g - (C0 + C1));
                    unsigned m = (4u * q) % 85u;    // float idx of v[j].x mod 85
                    if (m - 1u <= 3u) {             // m in [1,4] -> contains a ch4
                        float4 vv = v[j];
                        float x = (m == 4u) ? vv.x : (m == 3u) ? vv.y
                                : (m == 2u) ? vv.z : vv.w;
                        // -log1p(-clip(sigmoid(x),1e-10,1-1e-10)) == min(softplus(x), -ln(1e-10))
                        float sp = fmaxf(x, 0.f) + log1pf(expf(-fabsf(x)));
                        float bce = fminf(sp, 23.02585093f);
                        if (g < C0)           s0 += bce;
                        else if (g < C0 + C1) s1 += bce;
                        else                  s2 += bce;
                    }
                }
            }
        }
        #pragma unroll
        for (int off = 32; off > 0; off >>= 1) {
            s0 += __shfl_xor(s0, off, 64);
            s1 += __shfl_xor(s1, off, 64);
            s2 += __shfl_xor(s2, off, 64);
        }
        if (lane == 0) { sm3[wv][0] = s0; sm3[wv][1] = s1; sm3[wv][2] = s2; }
        __syncthreads();
        if (threadIdx.x < 3)
            noobj_part[nb * 3 + threadIdx.x] =
                sm3[0][threadIdx.x] + sm3[1][threadIdx.x] + sm3[2][threadIdx.x] + sm3[3][threadIdx.x];
    } else {
        // ---------- positive cells: one WAVE per (scale, order) ----------
        int bp = blk;
        int s = bp / POS_BLOCKS_PER_SCALE;
        int order = (bp % POS_BLOCKS_PER_SCALE) * 4 + wv;   // < 800

        float v_coord = 0.f, v_obj = 0.f, v_noadj = 0.f, v_cls = 0.f, v_np = 0.f;

        int b = order / TT, t = order % TT;
        const float* tr = targets + order * 85;
        float cx, cy, w, h; int best, gxi, gyi;
        if (target_cell(tr, s, cx, cy, w, h, best, gxi, gyi) == 0) {  // wave-uniform
            int H = c_H[s];
            int flat = ((b * 3 + best) * H + gyi) * H + gxi;

            // inline last-write-wins: any LATER valid target in this image on same cell?
            bool lost = false;
            int tp = t + 1 + lane;
            if (tp < TT) {
                const float* tr2 = targets + (b * TT + tp) * 85;
                float cx2, cy2, w2, h2; int best2, gxi2, gyi2;
                if (target_cell(tr2, s, cx2, cy2, w2, h2, best2, gxi2, gyi2) == 0) {
                    int flat2 = ((b * 3 + best2) * H + gyi2) * H + gxi2;
                    lost = (flat2 == flat);
                }
            }
            if (__ballot(lost) == 0ull) {   // this order wins the cell
                const float* pred = (s == 0) ? p0 : (s == 1) ? p1 : p2;
                const float* pc = pred + (long long)flat * 85;

                float px = sigmoidf_(pc[0]);
                float py = sigmoidf_(pc[1]);
                float bx = clipf_((px + (float)gxi) / (float)H, 0.f, 1.f);
                float by = clipf_((py + (float)gyi) / (float)H, 0.f, 1.f);
                float aw = c_anchors[s][best][0], ah = c_anchors[s][best][1];
                float bwv = clipf_(expf(clipf_(pc[2], -10.f, 10.f)) * aw / IMGF, 0.f, 1.f);
                float bhv = clipf_(expf(clipf_(pc[3], -10.f, 10.f)) * ah / IMGF, 0.f, 1.f);
                float iou = iou4(bx, by, bwv, bhv, cx, cy, w, h);

                float p = clipf_(sigmoidf_(pc[4]), 1e-10f, 1.0f);

                // class BCE split across lanes: lane k -> class k (+ class k+64 if k<16)
                float pcv = clipf_(sigmoidf_(pc[5 + lane]), 1e-10f, 1.0f);
                float tc  = clipf_(tr[5 + lane], 0.f, 1.f);
                float cl  = -(tc * logf(pcv) + (1.f - tc) * log1pf(-pcv));
                if (lane < NCLS - 64) {
                    float pcv2 = clipf_(sigmoidf_(pc[5 + 64 + lane]), 1e-10f, 1.0f);
                    float tc2  = clipf_(tr[5 + 64 + lane], 0.f, 1.f);
                    cl += -(tc2 * logf(pcv2) + (1.f - tc2) * log1pf(-pcv2));
                }
                #pragma unroll
                for (int off = 32; off > 0; off >>= 1) cl += __shfl_xor(cl, off, 64);

                v_coord = 1.f - iou;
                v_obj   = -logf(p);
                v_noadj = -log1pf(-p);
                v_cls   = cl;
                v_np    = 1.f;
            }
        }

        if (lane == 0) {
            sm5[wv][0] = v_coord; sm5[wv][1] = v_obj; sm5[wv][2] = v_noadj;
            sm5[wv][3] = v_cls;   sm5[wv][4] = v_np;
        }
        __syncthreads();
        if (threadIdx.x < 5) {
            pos_part[bp * 5 + threadIdx.x] =
                sm5[0][threadIdx.x] + sm5[1][threadIdx.x] +
                sm5[2][threadIdx.x] + sm5[3][threadIdx.x];
        }
    }
}

// ---- kernel D: reduce partials + final combine ----
__global__ __launch_bounds__(256) void k_final(const float* __restrict__ noobj_part,
                                               const float* __restrict__ pos_part,
                                               float* __restrict__ out) {
    float nsum[3] = {0.f, 0.f, 0.f};
    #pragma unroll
    for (int r = 0; r < 4; r++) {                  // 1024/256 = 4 rounds
        int i = threadIdx.x + r * 256;
        nsum[0] += noobj_part[i * 3 + 0];
        nsum[1] += noobj_part[i * 3 + 1];
        nsum[2] += noobj_part[i * 3 + 2];
    }
    float ps[3][5] = {};
    for (int i = threadIdx.x; i < NPOS_BLOCKS; i += 256) {
        int s = i / POS_BLOCKS_PER_SCALE;
        #pragma unroll
        for (int q = 0; q < 5; q++) ps[s][q] += pos_part[i * 5 + q];
    }

    __shared__ float red[18][256];
    #pragma unroll
    for (int s = 0; s < 3; s++) {
        red[s][threadIdx.x] = nsum[s];
        #pragma unroll
        for (int q = 0; q < 5; q++) red[3 + s * 5 + q][threadIdx.x] = ps[s][q];
    }
    __syncthreads();
    for (int off = 128; off > 0; off >>= 1) {
        if (threadIdx.x < off) {
            #pragma unroll
            for (int r = 0; r < 18; r++)
                red[r][threadIdx.x] += red[r][threadIdx.x + off];
        }
        __syncthreads();
    }
    if (threadIdx.x == 0) {
        const float ncell[3] = {(float)N0, (float)N1, (float)N2};
        float coord = 0.f, conf = 0.f, cls = 0.f;
        #pragma unroll
        for (int s = 0; s < 3; s++) {
            float noobjTot = red[s][0];
            float co    = red[3 + s * 5 + 0][0];
            float ob    = red[3 + s * 5 + 1][0];
            float noadj = red[3 + s * 5 + 2][0];
            float cl    = red[3 + s * 5 + 3][0];
            float npos  = red[3 + s * 5 + 4][0];
            float nneg = ncell[s] - npos;
            float dn = fmaxf(npos, 1.f);
            conf += ob / dn + 0.5f * (noobjTot - noadj) / fmaxf(nneg, 1.f);
            if (npos > 0.f) {
                coord += co / dn;
                cls   += cl / fmaxf(npos * (float)NCLS, 1.f);
            }
        }
        out[0] = 5.0f * coord + conf + 1.0f * cls;
        out[1] = coord;
        out[2] = conf;
        out[3] = cls;
    }
}

extern "C" void kernel_launch(void* const* d_in, const int* in_sizes, int n_in,
                              void* d_out, int out_size, void* d_ws, size_t ws_size,
                              hipStream_t stream) {
    const float* p0 = (const float*)d_in[0];
    const float* p1 = (const float*)d_in[1];
    const float* p2 = (const float*)d_in[2];
    const float* tg = (const float*)d_in[3];
    float* out = (float*)d_out;

    char* ws = (char*)d_ws;
    float* noobj_part = (float*)ws;              // NOB*3 floats (12 KB)
    float* pos_part   = (float*)(ws + 16384);    // NPOS_BLOCKS*5 floats (12 KB)

    k_main<<<NBLK, 256, 0, stream>>>(p0, p1, p2, tg, noobj_part, pos_part);
    k_final<<<1, 256, 0, stream>>>(noobj_part, pos_part, out);
}

// Round 3
// 175.551 us; speedup vs baseline: 1.3391x; 1.0133x over previous
//
#include <hip/hip_runtime.h>
#include <math.h>

// ---------------- problem constants ----------------
#define BB   16      // batch
#define TT   50      // targets per image
#define NCLS 80
#define IMGF 608.0f

#define H0 76
#define H1 38
#define H2 19
#define N0 277248   // 16*3*76*76
#define N1 69312    // 16*3*38*38
#define N2 17328    // 16*3*19*19

// float4 counts per scale (N*85/4 — all divisible by 4)
#define C0 5891520
#define C1 1472880
#define C2 368220

// pos: one WAVE per (scale, order). 200 blocks/scale * 4 waves = 800 orders.
#define POS_BLOCKS_PER_SCALE 200
#define NPOS_BLOCKS (3*POS_BLOCKS_PER_SCALE)   // 600

// noobj (R8): coalesced float4 stream, VALU-light.
// R2 post-mortem: stream was VALU-issue-bound (53% VALUBusy) — divergent
// softplus branch fired every batch (3 useful lanes/wave) with library
// log1pf/expf (~60 inst), plus per-float4 array-select compares. Fixes:
// per-scale BLOCK RANGES (pointer/count wave-uniform) + __expf/__logf
// hardware transcendentals (~8 ops). Memory floor ~16-22us for 115.5MB.
#define F4_PER_THREAD 30
#define F4_PER_BLOCK (256*F4_PER_THREAD)       // 7680
#define NOB0 768   // ceil(C0/7680) = 767.1
#define NOB1 192   // ceil(C1/7680) = 191.8
#define NOB2 48    // ceil(C2/7680) = 47.9
#define NOBT (NOB0+NOB1+NOB2)                  // 1008
#define NBLK (NOBT + NPOS_BLOCKS)              // 1608

__constant__ float c_anchors[3][3][2] = {
    {{12.f,16.f},{19.f,36.f},{40.f,28.f}},
    {{36.f,75.f},{76.f,55.f},{72.f,146.f}},
    {{142.f,110.f},{192.f,243.f},{459.f,401.f}}};
__constant__ int c_H[3] = {H0, H1, H2};

__device__ __forceinline__ float sigmoidf_(float x) { return 1.0f / (1.0f + expf(-x)); }
__device__ __forceinline__ float clipf_(float x, float lo, float hi) {
    return fminf(fmaxf(x, lo), hi);
}

__device__ __forceinline__ float iou4(float ax, float ay, float aw, float ah,
                                      float bx, float by, float bw, float bh) {
    float ax1 = ax - aw * 0.5f, ay1 = ay - ah * 0.5f;
    float ax2 = ax + aw * 0.5f, ay2 = ay + ah * 0.5f;
    float bx1 = bx - bw * 0.5f, by1 = by - bh * 0.5f;
    float bx2 = bx + bw * 0.5f, by2 = by + bh * 0.5f;
    float iw = fmaxf(fminf(ax2, bx2) - fmaxf(ax1, bx1), 0.f);
    float ih = fmaxf(fminf(ay2, by2) - fmaxf(ay1, by1), 0.f);
    float inter = iw * ih;
    float uni = (ax2 - ax1) * (ay2 - ay1) + (bx2 - bx1) * (by2 - by1) - inter + 1e-7f;
    return inter / uni;
}

// anchor match + cell for one (scale, target row). returns -1 if invalid target
__device__ __forceinline__ int target_cell(const float* tr, int s, float& cx, float& cy,
                                           float& w, float& h, int& best, int& gxi, int& gyi) {
    float t4 = tr[4];
    if (!(t4 > 0.f)) return -1;
    cx = clipf_(tr[0], 0.f, 1.f);
    cy = clipf_(tr[1], 0.f, 1.f);
    w  = clipf_(tr[2], 0.f, 1.f);
    h  = clipf_(tr[3], 0.f, 1.f);
    best = 0;
    float bi = -1e30f;
    #pragma unroll
    for (int a = 0; a < 3; a++) {
        float aw = c_anchors[s][a][0] / IMGF;
        float ah = c_anchors[s][a][1] / IMGF;
        float v = iou4(0.5f, 0.5f, aw, ah, cx, cy, w, h);
        if (v > bi) { bi = v; best = a; }  // first-max == jnp.argmax
    }
    int H = c_H[s];
    gxi = (int)(cx * (float)H); gxi = min(max(gxi, 0), H - 1);
    gyi = (int)(cy * (float)H); gyi = min(max(gyi, 0), H - 1);
    return 0;
}

// ---- main kernel: blocks [0,NOBT) = noobj stream (per-scale ranges);
//      blocks [NOBT,NBLK) = positive waves. Two dispatches kept: grid-wide
//      sync costs ~50us on 8 XCDs (R6) vs ~5-10us dispatch bubble. ----
__global__ __launch_bounds__(256) void k_main(const float* __restrict__ p0,
                                              const float* __restrict__ p1,
                                              const float* __restrict__ p2,
                                              const float* __restrict__ targets,
                                              float* __restrict__ noobj_part,   // [NOBT]
                                              float* __restrict__ pos_part) {   // [NPOS_BLOCKS*5]
    int blk = blockIdx.x;
    int lane = threadIdx.x & 63;
    int wv = threadIdx.x >> 6;

    __shared__ float sm1[4];
    __shared__ float sm5[4][5];

    if (blk < NOBT) {
        // ---------- no-object BCE: coalesced float4 stream, one scale per block ----------
        const float4* pv; unsigned cnt; int rb;
        if (blk < NOB0)             { pv = (const float4*)p0; cnt = C0; rb = blk; }
        else if (blk < NOB0 + NOB1) { pv = (const float4*)p1; cnt = C1; rb = blk - NOB0; }
        else                        { pv = (const float4*)p2; cnt = C2; rb = blk - NOB0 - NOB1; }
        unsigned gbase = (unsigned)rb * F4_PER_BLOCK + threadIdx.x;

        float s = 0.f;
        #pragma unroll 1
        for (int c = 0; c < 6; c++) {               // 6 chunks x 5 float4s = 30
            float4 v[5];
            #pragma unroll
            for (int j = 0; j < 5; j++) {           // 5 loads in flight (MLP)
                unsigned q = gbase + (c * 5 + j) * 256;
                v[j] = (q < cnt) ? pv[q] : make_float4(0.f, 0.f, 0.f, 0.f);
            }
            #pragma unroll
            for (int j = 0; j < 5; j++) {
                unsigned q = gbase + (c * 5 + j) * 256;
                if (q < cnt) {
                    unsigned m = (4u * q) % 85u;    // float idx of v[j].x mod 85
                    if (m - 1u <= 3u) {             // m in [1,4] -> contains a ch4
                        float4 vv = v[j];
                        float x = (m == 4u) ? vv.x : (m == 3u) ? vv.y
                                : (m == 2u) ? vv.z : vv.w;
                        // -log1p(-clip(sigmoid(x),1e-10,1-1e-10)) == min(softplus(x), -ln(1e-10))
                        // HW trans pipe: __expf/__logf (err ~1e-7 abs -> ~1e-9 rel on output)
                        float sp = fmaxf(x, 0.f) + __logf(1.f + __expf(-fabsf(x)));
                        s += fminf(sp, 23.02585093f);
                    }
                }
            }
        }
        #pragma unroll
        for (int off = 32; off > 0; off >>= 1) s += __shfl_xor(s, off, 64);
        if (lane == 0) sm1[wv] = s;
        __syncthreads();
        if (threadIdx.x == 0)
            noobj_part[blk] = sm1[0] + sm1[1] + sm1[2] + sm1[3];
    } else {
        // ---------- positive cells: one WAVE per (scale, order) ----------
        int bp = blk - NOBT;
        int s = bp / POS_BLOCKS_PER_SCALE;
        int order = (bp % POS_BLOCKS_PER_SCALE) * 4 + wv;   // < 800

        float v_coord = 0.f, v_obj = 0.f, v_noadj = 0.f, v_cls = 0.f, v_np = 0.f;

        int b = order / TT, t = order % TT;
        const float* tr = targets + order * 85;
        float cx, cy, w, h; int best, gxi, gyi;
        if (target_cell(tr, s, cx, cy, w, h, best, gxi, gyi) == 0) {  // wave-uniform
            int H = c_H[s];
            int flat = ((b * 3 + best) * H + gyi) * H + gxi;

            // inline last-write-wins: any LATER valid target in this image on same cell?
            bool lost = false;
            int tp = t + 1 + lane;
            if (tp < TT) {
                const float* tr2 = targets + (b * TT + tp) * 85;
                float cx2, cy2, w2, h2; int best2, gxi2, gyi2;
                if (target_cell(tr2, s, cx2, cy2, w2, h2, best2, gxi2, gyi2) == 0) {
                    int flat2 = ((b * 3 + best2) * H + gyi2) * H + gxi2;
                    lost = (flat2 == flat);
                }
            }
            if (__ballot(lost) == 0ull) {   // this order wins the cell
                const float* pred = (s == 0) ? p0 : (s == 1) ? p1 : p2;
                const float* pc = pred + (long long)flat * 85;

                float px = sigmoidf_(pc[0]);
                float py = sigmoidf_(pc[1]);
                float bx = clipf_((px + (float)gxi) / (float)H, 0.f, 1.f);
                float by = clipf_((py + (float)gyi) / (float)H, 0.f, 1.f);
                float aw = c_anchors[s][best][0], ah = c_anchors[s][best][1];
                float bwv = clipf_(expf(clipf_(pc[2], -10.f, 10.f)) * aw / IMGF, 0.f, 1.f);
                float bhv = clipf_(expf(clipf_(pc[3], -10.f, 10.f)) * ah / IMGF, 0.f, 1.f);
                float iou = iou4(bx, by, bwv, bhv, cx, cy, w, h);

                float p = clipf_(sigmoidf_(pc[4]), 1e-10f, 1.0f);

                // class BCE split across lanes: lane k -> class k (+ class k+64 if k<16)
                float pcv = clipf_(sigmoidf_(pc[5 + lane]), 1e-10f, 1.0f);
                float tc  = clipf_(tr[5 + lane], 0.f, 1.f);
                float cl  = -(tc * logf(pcv) + (1.f - tc) * log1pf(-pcv));
                if (lane < NCLS - 64) {
                    float pcv2 = clipf_(sigmoidf_(pc[5 + 64 + lane]), 1e-10f, 1.0f);
                    float tc2  = clipf_(tr[5 + 64 + lane], 0.f, 1.f);
                    cl += -(tc2 * logf(pcv2) + (1.f - tc2) * log1pf(-pcv2));
                }
                #pragma unroll
                for (int off = 32; off > 0; off >>= 1) cl += __shfl_xor(cl, off, 64);

                v_coord = 1.f - iou;
                v_obj   = -logf(p);
                v_noadj = -log1pf(-p);
                v_cls   = cl;
                v_np    = 1.f;
            }
        }

        if (lane == 0) {
            sm5[wv][0] = v_coord; sm5[wv][1] = v_obj; sm5[wv][2] = v_noadj;
            sm5[wv][3] = v_cls;   sm5[wv][4] = v_np;
        }
        __syncthreads();
        if (threadIdx.x < 5) {
            pos_part[bp * 5 + threadIdx.x] =
                sm5[0][threadIdx.x] + sm5[1][threadIdx.x] +
                sm5[2][threadIdx.x] + sm5[3][threadIdx.x];
        }
    }
}

// ---- kernel D: reduce partials + final combine ----
__global__ __launch_bounds__(256) void k_final(const float* __restrict__ noobj_part,
                                               const float* __restrict__ pos_part,
                                               float* __restrict__ out) {
    float n0 = 0.f, n1 = 0.f, n2 = 0.f;
    #pragma unroll
    for (int r = 0; r < 4; r++) {                  // covers 1024 >= 1008
        int i = threadIdx.x + r * 256;
        if (i < NOB0)                    n0 += noobj_part[i];
        else if (i < NOB0 + NOB1)        n1 += noobj_part[i];
        else if (i < NOBT)               n2 += noobj_part[i];
    }
    float ps[3][5] = {};
    for (int i = threadIdx.x; i < NPOS_BLOCKS; i += 256) {
        int s = i / POS_BLOCKS_PER_SCALE;
        #pragma unroll
        for (int q = 0; q < 5; q++) ps[s][q] += pos_part[i * 5 + q];
    }

    __shared__ float red[18][256];
    red[0][threadIdx.x] = n0;
    red[1][threadIdx.x] = n1;
    red[2][threadIdx.x] = n2;
    #pragma unroll
    for (int s = 0; s < 3; s++) {
        #pragma unroll
        for (int q = 0; q < 5; q++) red[3 + s * 5 + q][threadIdx.x] = ps[s][q];
    }
    __syncthreads();
    for (int off = 128; off > 0; off >>= 1) {
        if (threadIdx.x < off) {
            #pragma unroll
            for (int r = 0; r < 18; r++)
                red[r][threadIdx.x] += red[r][threadIdx.x + off];
        }
        __syncthreads();
    }
    if (threadIdx.x == 0) {
        const float ncell[3] = {(float)N0, (float)N1, (float)N2};
        float coord = 0.f, conf = 0.f, cls = 0.f;
        #pragma unroll
        for (int s = 0; s < 3; s++) {
            float noobjTot = red[s][0];
            float co    = red[3 + s * 5 + 0][0];
            float ob    = red[3 + s * 5 + 1][0];
            float noadj = red[3 + s * 5 + 2][0];
            float cl    = red[3 + s * 5 + 3][0];
            float npos  = red[3 + s * 5 + 4][0];
            float nneg = ncell[s] - npos;
            float dn = fmaxf(npos, 1.f);
            conf += ob / dn + 0.5f * (noobjTot - noadj) / fmaxf(nneg, 1.f);
            if (npos > 0.f) {
                coord += co / dn;
                cls   += cl / fmaxf(npos * (float)NCLS, 1.f);
            }
        }
        out[0] = 5.0f * coord + conf + 1.0f * cls;
        out[1] = coord;
        out[2] = conf;
        out[3] = cls;
    }
}

extern "C" void kernel_launch(void* const* d_in, const int* in_sizes, int n_in,
                              void* d_out, int out_size, void* d_ws, size_t ws_size,
                              hipStream_t stream) {
    const float* p0 = (const float*)d_in[0];
    const float* p1 = (const float*)d_in[1];
    const float* p2 = (const float*)d_in[2];
    const float* tg = (const float*)d_in[3];
    float* out = (float*)d_out;

    char* ws = (char*)d_ws;
    float* noobj_part = (float*)ws;              // NOBT floats (4032 B)
    float* pos_part   = (float*)(ws + 8192);     // NPOS_BLOCKS*5 floats (12 KB)

    k_main<<<NBLK, 256, 0, stream>>>(p0, p1, p2, tg, noobj_part, pos_part);
    k_final<<<1, 256, 0, stream>>>(noobj_part, pos_part, out);
}